// Round 19
// baseline (21.943 us; speedup 1.0000x reference)
//
#include <hip/hip_runtime.h>
#include <hip/hip_fp16.h>

#define BATCH  1024
#define NVARS  2048
#define N_OUT  4096

#define W16BYTES (NVARS * 32)    // 64 KiB per 16-col window (fp16, row = 32 B)
#define NW16     (BATCH / 16)    // 64 windows

typedef float f32x4 __attribute__((ext_vector_type(4)));
typedef unsigned u32x4 __attribute__((ext_vector_type(4)));

__device__ __forceinline__ __half2 u2h2(unsigned u) {
    union { unsigned u; __half2 h; } c; c.u = u; return c.h;
}
__device__ __forceinline__ unsigned h22u(__half2 h) {
    union { unsigned u; __half2 h; } c; c.h = h; return c.u;
}
__device__ __forceinline__ void sel2sc(unsigned sel, unsigned& s, unsigned& c) {
    // half2 constants: 1.0h2 = 0x3C003C00, -1.0h2 = 0xBC00BC00
    c = (sel & 1u) ? 0x3C003C00u : 0u;
    s = (sel == 2u) ? 0x3C003C00u : (sel == 3u) ? 0xBC00BC00u : 0u;
}

// ---------------- prep: transpose to 16-col-window fp16 + T-flatten ----------
// xh2: [64 w16][2048 r][16 cols fp16 = 32 B]; byte(w16,r) = w16*65536 + r*32
// T[i*8+m] = leafA | leafB<<16, leaf = sel<<11 | row. sel:0->0,1->1,2->x,3->1-x
// All outputs NT so main's XCD-affine stage pulls clean lines into its own L2.
__global__ __launch_bounds__(256) void prep_kernel(
    const float* __restrict__ x,
    const int2* __restrict__ idx0,
    const int2* __restrict__ idx1,
    const int2* __restrict__ idx2,
    const int2* __restrict__ idx3,
    unsigned* __restrict__ T,
    char* __restrict__ xh2)
{
    __shared__ char tile[64 * 272];    // 64 rows x 128 cols fp16, 272B padded rows

    const int bid = blockIdx.x;        // 256 blocks
    const int tid = threadIdx.x;
    const int rt  = bid >> 3;          // row tile 0..31
    const int ct  = bid & 7;           // col tile 0..7 (128 cols each)
    const int r0  = rt * 64;

    // ---- T-flatten on blocks 0..15 ----
    if (bid < 16) {
        const int i = bid * 256 + tid;
        int2 p3 = idx3[i];
        int n = 0;
        #pragma unroll
        for (int t = 0; t < 2; ++t) {
            int2 p2 = idx2[t ? p3.y : p3.x];
            #pragma unroll
            for (int u = 0; u < 2; ++u) {
                int2 p1 = idx1[u ? p2.y : p2.x];
                #pragma unroll
                for (int v = 0; v < 2; ++v) {
                    int2 p0 = idx0[v ? p1.y : p1.x];
                    unsigned w = 0;
                    #pragma unroll
                    for (int e = 0; e < 2; ++e) {
                        int k = e ? p0.y : p0.x;
                        unsigned code;
                        if (k < 2) code = (unsigned)k << 11;
                        else       code = ((2u + (k & 1)) << 11) | ((unsigned)(k - 2) >> 1);
                        w |= code << (16 * e);
                    }
                    __builtin_nontemporal_store(w, &T[(size_t)i * 8 + n]);
                    ++n;
                }
            }
        }
    }

    // ---- phase A: coalesced read of 64 rows x 128 cols, cvt fp16 into tile ----
    {
        const int r_l = tid >> 5;      // 0..7
        const int c4  = tid & 31;      // 0..31 float4 units
        #pragma unroll
        for (int q = 0; q < 8; ++q) {
            const int rr = q * 8 + r_l;                 // tile row 0..63
            float4 v = ((const float4*)x)[(size_t)(r0 + rr) * 256 + ct * 32 + c4];
            unsigned h0 = h22u(__floats2half2_rn(v.x, v.y));
            unsigned h1 = h22u(__floats2half2_rn(v.z, v.w));
            unsigned* p = (unsigned*)(tile + rr * 272 + c4 * 8);
            p[0] = h0; p[1] = h1;
        }
    }
    __syncthreads();

    // ---- phase B: write w16-major NT; 64 lanes = 1 KB contiguous per inst ----
    {
        #pragma unroll
        for (int it = 0; it < 4; ++it) {
            const int idx = it * 256 + tid;    // 0..1023 = (g, r2, q)
            const int q  = idx & 1;
            const int r2 = (idx >> 1) & 63;
            const int g  = idx >> 7;           // window-in-tile 0..7
            u32x4 v = *reinterpret_cast<const u32x4*>(tile + r2 * 272 + g * 32 + q * 16);
            const int w16 = ct * 8 + g;
            __builtin_nontemporal_store(
                v, reinterpret_cast<u32x4*>(
                       xh2 + (size_t)w16 * W16BYTES + (r0 + r2) * 32 + q * 16));
        }
    }
}

// ---------------- main: 64 KiB window, 2 blocks/CU generation pipelining -------
// 512 blocks x 512 threads, __launch_bounds__(512,4) (<=128 VGPR), 64 KiB LDS
// -> 2 co-resident blocks/CU: one block's stage/store overlaps the other's
// compute. XCD k (= bx&7) owns windows 8k..8k+7 (x slice + out slice local).
// LDS swizzle: byte(r, 16B-piece q) = (r*32 + q*16) ^ ((r&7)<<4) -> 8
// consecutive rows cover all 32 banks (row-stride-32 unswizzled pins base
// banks to 4 positions = R17's regression).
// Thread = (output ol 0..127, cg 0..3 = 4 cols); 4 passes x 128 outputs.
// Leaf read = ds_read_b64 at ((r*32+(cg>>1)*16)^((r&7)<<4)) + (cg&1)*8.
// Stores: lanes 4i..4i+3 = 64 B contiguous NT runs.
__global__ __launch_bounds__(512, 4) void knowledge_main(
    const char* __restrict__ xh2,
    const uint4* __restrict__ T4,     // 2 x uint4 per output (8 packed pair-words)
    float* __restrict__ out)
{
    __shared__ char lds[65536];

    const int bx    = blockIdx.x;     // 512
    const int tid   = threadIdx.x;    // 0..511
    const int xcd   = bx & 7;
    const int slot  = bx >> 3;        // 0..63
    const int w16   = xcd * 8 + (slot & 7);  // window 0..63 (cols w16*16..+15)
    const int chunk = slot >> 3;      // 0..7 (512 outputs each)

    const int cg = tid & 3;           // 4-col group (8 B fp16)
    const int ol = tid >> 2;          // output-in-pass 0..127
    const int cq = (cg >> 1) << 4;    // 16B-piece offset
    const int cd = (cg & 1) << 3;     // 8B offset within piece

    // ---- issue pass-0 T loads FIRST: latency hides under staging ----
    int o = chunk * 512 + ol;
    uint4 t0 = T4[(size_t)o * 2];
    uint4 t1 = T4[(size_t)o * 2 + 1];

    // ---- stage: 64 KiB contiguous from xh2, swizzled LDS writes ----
    {
        const char* src = xh2 + (size_t)w16 * W16BYTES;
        #pragma unroll
        for (int it = 0; it < 8; ++it) {
            const int idx = it * 512 + tid;    // 16-B unit 0..4095
            uint4 v = *(const uint4*)(src + idx * 16);
            const int r = idx >> 1, q = idx & 1;
            *(uint4*)(lds + ((r * 32 + q * 16) ^ ((r & 7) << 4))) = v;
        }
    }
    __syncthreads();

    #pragma unroll 1
    for (int pass = 0; pass < 4; ++pass) {
        const unsigned tw[8] = {t0.x, t0.y, t0.z, t0.w, t1.x, t1.y, t1.z, t1.w};

        // prefetch next pass's T while this pass computes
        if (pass < 3) {
            t0 = T4[(size_t)(o + 128) * 2];
            t1 = T4[(size_t)(o + 128) * 2 + 1];
        }

        float accf[4];
        #pragma unroll
        for (int k = 0; k < 4; ++k) accf[k] = 0.f;

        #pragma unroll
        for (int a3 = 0; a3 < 2; ++a3) {                 // top SumLayer
            __half2 prod2[2];
            #pragma unroll
            for (int a2 = 0; a2 < 2; ++a2) {             // ProductLayer
                __half2 sum1[2];
                #pragma unroll
                for (int a1 = 0; a1 < 2; ++a1) {         // SumLayer
                    const int m = a3 * 4 + a2 * 2 + a1;
                    const unsigned wv = tw[m];
                    const int rA = (int)(wv & 0x7FFu);
                    const int rB = (int)((wv >> 16) & 0x7FFu);
                    uint2 A = *(const uint2*)(lds + (((rA * 32 + cq) ^ ((rA & 7) << 4)) + cd));
                    uint2 B = *(const uint2*)(lds + (((rB * 32 + cq) ^ ((rB & 7) << 4)) + cd));
                    unsigned sa, ca, sb, cb;
                    sel2sc((wv >> 11) & 3u, sa, ca);
                    sel2sc((wv >> 27) & 3u, sb, cb);
                    const unsigned aw[2] = {A.x, A.y};
                    const unsigned bw[2] = {B.x, B.y};
                    #pragma unroll
                    for (int k = 0; k < 2; ++k) {
                        __half2 va = __hfma2(u2h2(aw[k]), u2h2(sa), u2h2(ca));
                        __half2 vb = __hfma2(u2h2(bw[k]), u2h2(sb), u2h2(cb));
                        __half2 pr = __hmul2(va, vb);    // leaf product
                        sum1[k] = (a1 == 0) ? pr : __hadd2(sum1[k], pr);
                    }
                }
                #pragma unroll
                for (int k = 0; k < 2; ++k)
                    prod2[k] = (a2 == 0) ? sum1[k] : __hmul2(prod2[k], sum1[k]);
            }
            #pragma unroll
            for (int k = 0; k < 2; ++k) {                // top sum in f32
                float2 pf = __half22float2(prod2[k]);
                accf[2 * k]     += pf.x;
                accf[2 * k + 1] += pf.y;
            }
        }

        // lanes 4i..4i+3 cover 16 cols of row o = 64 B contiguous
        float* dst = out + (size_t)o * BATCH + w16 * 16 + cg * 4;
        f32x4 ov = {accf[0], accf[1], accf[2], accf[3]};
        __builtin_nontemporal_store(ov, reinterpret_cast<f32x4*>(dst));

        o += 128;
    }
}

// ---------------- fallback (round-1 kernel) if ws too small ----------------
__device__ __forceinline__ float Hval(int k, const float* __restrict__ x, int b) {
    if (k < 2) return (float)k;
    float v = x[((k - 2) >> 1) * BATCH + b];
    return (k & 1) ? 1.0f - v : v;
}

__global__ __launch_bounds__(256) void knowledge_fused_kernel(
    const float* __restrict__ x,
    const int2* __restrict__ idx0,
    const int2* __restrict__ idx1,
    const int2* __restrict__ idx2,
    const int2* __restrict__ idx3,
    float* __restrict__ out)
{
    const int i = blockIdx.x;
    const int b = blockIdx.y * blockDim.x + threadIdx.x;
    const int2 p3 = idx3[i];
    float acc3 = 0.0f;
    #pragma unroll
    for (int t = 0; t < 2; ++t) {
        const int2 p2 = idx2[t ? p3.y : p3.x];
        float prod2 = 1.0f;
        #pragma unroll
        for (int u = 0; u < 2; ++u) {
            const int2 p1 = idx1[u ? p2.y : p2.x];
            float sum1 = 0.0f;
            #pragma unroll
            for (int v = 0; v < 2; ++v) {
                const int2 p0 = idx0[v ? p1.y : p1.x];
                sum1 += Hval(p0.x, x, b) * Hval(p0.y, x, b);
            }
            prod2 *= sum1;
        }
        acc3 += prod2;
    }
    out[(size_t)i * BATCH + b] = acc3;
}

extern "C" void kernel_launch(void* const* d_in, const int* in_sizes, int n_in,
                              void* d_out, int out_size, void* d_ws, size_t ws_size,
                              hipStream_t stream) {
    const float* x    = (const float*)d_in[0];
    const int2*  idx0 = (const int2*)d_in[1];
    const int2*  idx1 = (const int2*)d_in[2];
    const int2*  idx2 = (const int2*)d_in[3];
    const int2*  idx3 = (const int2*)d_in[4];
    float* out = (float*)d_out;

    const size_t t_bytes   = (size_t)N_OUT * 8 * sizeof(unsigned);   // 128 KB
    const size_t xh2_bytes = (size_t)NW16 * W16BYTES;                // 4 MB
    if (ws_size >= t_bytes + xh2_bytes) {
        unsigned* T   = (unsigned*)d_ws;
        char*     xh2 = (char*)d_ws + t_bytes;
        prep_kernel<<<256, 256, 0, stream>>>(x, idx0, idx1, idx2, idx3, T, xh2);
        knowledge_main<<<512, 512, 0, stream>>>(xh2, (const uint4*)T, out);
    } else {
        dim3 grid(N_OUT, BATCH / 256);
        knowledge_fused_kernel<<<grid, 256, 0, stream>>>(x, idx0, idx1, idx2, idx3, out);
    }
}

// Round 20
// 21.541 us; speedup vs baseline: 1.0187x; 1.0187x over previous
//
#include <hip/hip_runtime.h>
#include <hip/hip_fp16.h>

#define BATCH  1024
#define NVARS  2048
#define N_OUT  4096
#define MAGIC  0x13579BDFu

typedef float f32x4 __attribute__((ext_vector_type(4)));

__device__ __forceinline__ __half2 u2h2(unsigned u) {
    union { unsigned u; __half2 h; } c; c.u = u; return c.h;
}
__device__ __forceinline__ unsigned h22u(__half2 h) {
    union { unsigned u; __half2 h; } c; c.h = h; return c.u;
}
__device__ __forceinline__ void sel2sc(unsigned sel, unsigned& s, unsigned& c) {
    // half2 constants: 1.0h2 = 0x3C003C00, -1.0h2 = 0xBC00BC00
    c = (sel & 1u) ? 0x3C003C00u : 0u;
    s = (sel == 2u) ? 0x3C003C00u : (sel == 3u) ? 0xBC00BC00u : 0u;
}

// ---------------- single fused kernel, deduplicated T-walk ----------------
// 256 blocks x 1024 threads, 1 block/CU (128 KiB LDS) -> all blocks
// co-resident, so the flag spin cannot deadlock.
// Blocks 0..15: threads 0..255 walk the 4-level index tree for 256 outputs
// each (4096 total, ONCE chip-wide) -> T in ws -> threadfence + slot flag.
// All blocks: stage x window (overlaps the walk) -> spin on 16 slots ->
// R16-proven compute (2 passes x 256 outputs, cg leaf gathers, fp16 tree) ->
// full-line NT stores.
// Replay-safety: T is a pure function of the (unchanged) inputs, so any
// stale/concurrent read returns identical bytes; the flags only gate the
// first execution, where poisoned/zero ws != MAGIC forces a proper wait.
__global__ __launch_bounds__(1024) void knowledge_all(
    const float* __restrict__ x,
    const int2* __restrict__ idx0,
    const int2* __restrict__ idx1,
    const int2* __restrict__ idx2,
    const int2* __restrict__ idx3,
    unsigned* __restrict__ T,         // ws: 4096*8 words (128 KB)
    unsigned* __restrict__ slots,     // ws + 32768: 16 flag words
    float* __restrict__ out)
{
    __shared__ char lds[131072];      // window: row r at byte r*64 (32 fp16 cols)

    const int bx    = blockIdx.x;     // 256
    const int tid   = threadIdx.x;    // 0..1023
    const int xcd   = bx & 7;
    const int slot  = bx >> 3;        // 0..31
    const int w     = xcd * 4 + (slot & 3);  // window 0..31 (cols w*32..w*32+31)
    const int chunk = slot >> 2;      // 0..7 (512 outputs each)

    // ---- T-walk on blocks 0..15 (256 outputs each) ----
    if (bx < 16) {
        if (tid < 256) {
            const int i = bx * 256 + tid;
            int2 p3 = idx3[i];
            int n = 0;
            #pragma unroll
            for (int t = 0; t < 2; ++t) {
                int2 p2 = idx2[t ? p3.y : p3.x];
                #pragma unroll
                for (int u = 0; u < 2; ++u) {
                    int2 p1 = idx1[u ? p2.y : p2.x];
                    #pragma unroll
                    for (int v = 0; v < 2; ++v) {
                        int2 p0 = idx0[v ? p1.y : p1.x];
                        unsigned wc = 0;
                        #pragma unroll
                        for (int e = 0; e < 2; ++e) {
                            int k = e ? p0.y : p0.x;
                            unsigned code;
                            if (k < 2) code = (unsigned)k << 11;
                            else       code = ((2u + (k & 1)) << 11) | ((unsigned)(k - 2) >> 1);
                            wc |= code << (16 * e);
                        }
                        T[(size_t)i * 8 + n] = wc;
                        ++n;
                    }
                }
            }
        }
        __syncthreads();                       // all walker stores issued
        if (tid == 0) {
            __threadfence();                   // T visible device-wide
            atomicExch(&slots[bx], MAGIC);
        }
    }

    // ---- stage: x slice (2048 rows x 32 f32) -> LDS fp16 (overlaps walk) ----
    {
        const float4* x4 = (const float4*)x;   // row stride 256 float4
        #pragma unroll
        for (int it = 0; it < 16; ++it) {
            const int u = it * 1024 + tid;     // (row, 8B-piece): 2048*8 units
            const int r = u >> 3, p = u & 7;
            float4 v = x4[(size_t)r * 256 + w * 8 + p];
            uint2 d;
            d.x = h22u(__floats2half2_rn(v.x, v.y));
            d.y = h22u(__floats2half2_rn(v.z, v.w));
            *(uint2*)(lds + r * 64 + p * 8) = d;
        }
    }
    __syncthreads();

    // ---- wait until all 16 walker blocks have published T ----
    if (tid == 0) {
        unsigned pend;
        do {
            pend = 0;
            #pragma unroll
            for (int j = 0; j < 16; ++j)
                pend |= (atomicAdd(&slots[j], 0u) ^ MAGIC);
        } while (pend);
    }
    __syncthreads();

    // ---- compute: 2 passes x 256 outputs (R16-proven) ----
    const uint4* T4 = (const uint4*)T;
    const int cg  = tid & 3;          // col group 0..3 (8 cols)
    const int ol  = tid >> 2;         // output-in-pass 0..255
    const int cgb = cg * 16;          // byte offset within 64-B row

    int o = chunk * 512 + ol;         // pass-0 output
    uint4 t0 = T4[(size_t)o * 2];
    uint4 t1 = T4[(size_t)o * 2 + 1];

    #pragma unroll 1
    for (int pass = 0; pass < 2; ++pass) {
        const unsigned tw[8] = {t0.x, t0.y, t0.z, t0.w, t1.x, t1.y, t1.z, t1.w};

        // prefetch next pass's T while this pass computes
        if (pass == 0) {
            t0 = T4[(size_t)(o + 256) * 2];
            t1 = T4[(size_t)(o + 256) * 2 + 1];
        }

        float accf[8];
        #pragma unroll
        for (int k = 0; k < 8; ++k) accf[k] = 0.f;

        #pragma unroll
        for (int a3 = 0; a3 < 2; ++a3) {                 // top SumLayer
            __half2 prod2[4];
            #pragma unroll
            for (int a2 = 0; a2 < 2; ++a2) {             // ProductLayer
                __half2 sum1[4];
                #pragma unroll
                for (int a1 = 0; a1 < 2; ++a1) {         // SumLayer
                    const int m = a3 * 4 + a2 * 2 + a1;
                    const unsigned wv = tw[m];
                    uint4 A = *(const uint4*)(lds + ((wv & 0x7FFu) << 6) + cgb);
                    uint4 B = *(const uint4*)(lds + (((wv >> 16) & 0x7FFu) << 6) + cgb);
                    unsigned sa, ca, sb, cb;
                    sel2sc((wv >> 11) & 3u, sa, ca);
                    sel2sc((wv >> 27) & 3u, sb, cb);
                    const unsigned aw[4] = {A.x, A.y, A.z, A.w};
                    const unsigned bw[4] = {B.x, B.y, B.z, B.w};
                    #pragma unroll
                    for (int k = 0; k < 4; ++k) {
                        __half2 va = __hfma2(u2h2(aw[k]), u2h2(sa), u2h2(ca));
                        __half2 vb = __hfma2(u2h2(bw[k]), u2h2(sb), u2h2(cb));
                        __half2 pr = __hmul2(va, vb);    // leaf product
                        sum1[k] = (a1 == 0) ? pr : __hadd2(sum1[k], pr);
                    }
                }
                #pragma unroll
                for (int k = 0; k < 4; ++k)
                    prod2[k] = (a2 == 0) ? sum1[k] : __hmul2(prod2[k], sum1[k]);
            }
            #pragma unroll
            for (int k = 0; k < 4; ++k) {                // top sum in f32
                float2 pf = __half22float2(prod2[k]);
                accf[2 * k]     += pf.x;
                accf[2 * k + 1] += pf.y;
            }
        }

        // lanes 4i..4i+3 cover cols w*32..w*32+31 = 128 B contiguous (full line)
        float* dst = out + (size_t)o * BATCH + w * 32 + cg * 8;
        f32x4 o0 = {accf[0], accf[1], accf[2], accf[3]};
        f32x4 o1 = {accf[4], accf[5], accf[6], accf[7]};
        __builtin_nontemporal_store(o0, reinterpret_cast<f32x4*>(dst));
        __builtin_nontemporal_store(o1, reinterpret_cast<f32x4*>(dst) + 1);

        o += 256;
    }
}

// ---------------- fallback (round-1 kernel) if ws too small ----------------
__device__ __forceinline__ float Hval(int k, const float* __restrict__ x, int b) {
    if (k < 2) return (float)k;
    float v = x[((k - 2) >> 1) * BATCH + b];
    return (k & 1) ? 1.0f - v : v;
}

__global__ __launch_bounds__(256) void knowledge_fused_kernel(
    const float* __restrict__ x,
    const int2* __restrict__ idx0,
    const int2* __restrict__ idx1,
    const int2* __restrict__ idx2,
    const int2* __restrict__ idx3,
    float* __restrict__ out)
{
    const int i = blockIdx.x;
    const int b = blockIdx.y * blockDim.x + threadIdx.x;
    const int2 p3 = idx3[i];
    float acc3 = 0.0f;
    #pragma unroll
    for (int t = 0; t < 2; ++t) {
        const int2 p2 = idx2[t ? p3.y : p3.x];
        float prod2 = 1.0f;
        #pragma unroll
        for (int u = 0; u < 2; ++u) {
            const int2 p1 = idx1[u ? p2.y : p2.x];
            float sum1 = 0.0f;
            #pragma unroll
            for (int v = 0; v < 2; ++v) {
                const int2 p0 = idx0[v ? p1.y : p1.x];
                sum1 += Hval(p0.x, x, b) * Hval(p0.y, x, b);
            }
            prod2 *= sum1;
        }
        acc3 += prod2;
    }
    out[(size_t)i * BATCH + b] = acc3;
}

extern "C" void kernel_launch(void* const* d_in, const int* in_sizes, int n_in,
                              void* d_out, int out_size, void* d_ws, size_t ws_size,
                              hipStream_t stream) {
    const float* x    = (const float*)d_in[0];
    const int2*  idx0 = (const int2*)d_in[1];
    const int2*  idx1 = (const int2*)d_in[2];
    const int2*  idx2 = (const int2*)d_in[3];
    const int2*  idx3 = (const int2*)d_in[4];
    float* out = (float*)d_out;

    const size_t t_words = (size_t)N_OUT * 8;                       // 32768
    const size_t need    = (t_words + 16) * sizeof(unsigned);       // 128 KB + 64 B
    if (ws_size >= need) {
        unsigned* T     = (unsigned*)d_ws;
        unsigned* slots = (unsigned*)d_ws + t_words;
        knowledge_all<<<256, 1024, 0, stream>>>(x, idx0, idx1, idx2, idx3,
                                                T, slots, out);
    } else {
        dim3 grid(N_OUT, BATCH / 256);
        knowledge_fused_kernel<<<grid, 256, 0, stream>>>(x, idx0, idx1, idx2, idx3, out);
    }
}

// Round 21
// 20.261 us; speedup vs baseline: 1.0830x; 1.0631x over previous
//
#include <hip/hip_runtime.h>
#include <hip/hip_fp16.h>

#define BATCH  1024
#define NVARS  2048
#define N_OUT  4096

#define W32BYTES (NVARS * 64)    // 128 KB per 32-col window (fp16, row = 64 B)
#define NW32     (BATCH / 32)    // 32 windows

typedef float f32x4 __attribute__((ext_vector_type(4)));
typedef unsigned u32x4 __attribute__((ext_vector_type(4)));

__device__ __forceinline__ __half2 u2h2(unsigned u) {
    union { unsigned u; __half2 h; } c; c.u = u; return c.h;
}
__device__ __forceinline__ unsigned h22u(__half2 h) {
    union { unsigned u; __half2 h; } c; c.h = h; return c.u;
}
__device__ __forceinline__ void sel2sc(unsigned sel, unsigned& s, unsigned& c) {
    // half2 constants: 1.0h2 = 0x3C003C00, -1.0h2 = 0xBC00BC00
    c = (sel & 1u) ? 0x3C003C00u : 0u;
    s = (sel == 2u) ? 0x3C003C00u : (sel == 3u) ? 0xBC00BC00u : 0u;
}

// ---------------- prep: LDS-tile transpose to 32-col-window fp16 + T-flatten ----
// (R13 verbatim — proven best). xh2: [32 w][2048 r][32 cols fp16 = 64 B].
// T[i*8+m] = leafA | leafB<<16, leaf = sel<<11 | row. NT stores keep lines clean.
__global__ __launch_bounds__(256) void prep_kernel(
    const float* __restrict__ x,
    const int2* __restrict__ idx0,
    const int2* __restrict__ idx1,
    const int2* __restrict__ idx2,
    const int2* __restrict__ idx3,
    unsigned* __restrict__ T,
    char* __restrict__ xh2)
{
    __shared__ char tile[64 * 272];    // 64 rows x 128 cols fp16, 272B padded rows

    const int bid = blockIdx.x;        // 256 blocks
    const int tid = threadIdx.x;
    const int rt  = bid >> 3;          // row tile 0..31
    const int ct  = bid & 7;           // col tile 0..7 (128 cols each)
    const int r0  = rt * 64;

    if (bid < 16) {
        const int i = bid * 256 + tid;
        int2 p3 = idx3[i];
        int n = 0;
        #pragma unroll
        for (int t = 0; t < 2; ++t) {
            int2 p2 = idx2[t ? p3.y : p3.x];
            #pragma unroll
            for (int u = 0; u < 2; ++u) {
                int2 p1 = idx1[u ? p2.y : p2.x];
                #pragma unroll
                for (int v = 0; v < 2; ++v) {
                    int2 p0 = idx0[v ? p1.y : p1.x];
                    unsigned w = 0;
                    #pragma unroll
                    for (int e = 0; e < 2; ++e) {
                        int k = e ? p0.y : p0.x;
                        unsigned code;
                        if (k < 2) code = (unsigned)k << 11;
                        else       code = ((2u + (k & 1)) << 11) | ((unsigned)(k - 2) >> 1);
                        w |= code << (16 * e);
                    }
                    __builtin_nontemporal_store(w, &T[(size_t)i * 8 + n]);
                    ++n;
                }
            }
        }
    }

    {
        const int r_l = tid >> 5;      // 0..7
        const int c4  = tid & 31;      // 0..31 float4 units
        #pragma unroll
        for (int q = 0; q < 8; ++q) {
            const int rr = q * 8 + r_l;                 // tile row 0..63
            float4 v = ((const float4*)x)[(size_t)(r0 + rr) * 256 + ct * 32 + c4];
            unsigned h0 = h22u(__floats2half2_rn(v.x, v.y));
            unsigned h1 = h22u(__floats2half2_rn(v.z, v.w));
            unsigned* p = (unsigned*)(tile + rr * 272 + c4 * 8);
            p[0] = h0; p[1] = h1;
        }
    }
    __syncthreads();

    {
        const int wl = tid & 3;        // 16-B piece within 64-B row
        const int r2 = tid >> 2;       // 0..63
        #pragma unroll
        for (int g = 0; g < 4; ++g) {  // 32-col group within the 128-col tile
            u32x4 v = *reinterpret_cast<const u32x4*>(tile + r2 * 272 + g * 64 + wl * 16);
            const int w32 = ct * 4 + g;
            __builtin_nontemporal_store(
                v, reinterpret_cast<u32x4*>(
                       xh2 + (size_t)w32 * W32BYTES + (r0 + r2) * 64 + wl * 16));
        }
    }
}

// ---- gather-issue: unpack 8 packed pair-words, issue 16 ds_read_b128 ----
#define ISSUE16(TW, AA, T0, T1)                                               \
    do {                                                                      \
        TW[0]=(T0).x; TW[1]=(T0).y; TW[2]=(T0).z; TW[3]=(T0).w;               \
        TW[4]=(T1).x; TW[5]=(T1).y; TW[6]=(T1).z; TW[7]=(T1).w;               \
        _Pragma("unroll")                                                     \
        for (int m = 0; m < 8; ++m) {                                         \
            AA[2*m]   = *(const uint4*)(lds + ((TW[m] & 0x7FFu) << 6) + cgb); \
            AA[2*m+1] = *(const uint4*)(lds + (((TW[m] >> 16) & 0x7FFu) << 6) + cgb); \
        }                                                                     \
    } while (0)

// ---- math + NT store for one pass (consumes TW/AA register bank) ----
#define MATHSTORE(TW, AA, OO)                                                 \
    do {                                                                      \
        float accf[8];                                                        \
        _Pragma("unroll") for (int k = 0; k < 8; ++k) accf[k] = 0.f;          \
        _Pragma("unroll")                                                     \
        for (int a3 = 0; a3 < 2; ++a3) {                                      \
            __half2 prod2[4];                                                 \
            _Pragma("unroll")                                                 \
            for (int a2 = 0; a2 < 2; ++a2) {                                  \
                __half2 sum1[4];                                              \
                _Pragma("unroll")                                             \
                for (int a1 = 0; a1 < 2; ++a1) {                              \
                    const int m = a3 * 4 + a2 * 2 + a1;                       \
                    const unsigned wv = TW[m];                                \
                    unsigned sa, ca, sb, cb;                                  \
                    sel2sc((wv >> 11) & 3u, sa, ca);                          \
                    sel2sc((wv >> 27) & 3u, sb, cb);                          \
                    const unsigned aw[4] = {AA[2*m].x, AA[2*m].y, AA[2*m].z, AA[2*m].w}; \
                    const unsigned bw[4] = {AA[2*m+1].x, AA[2*m+1].y, AA[2*m+1].z, AA[2*m+1].w}; \
                    _Pragma("unroll")                                         \
                    for (int k = 0; k < 4; ++k) {                             \
                        __half2 va = __hfma2(u2h2(aw[k]), u2h2(sa), u2h2(ca)); \
                        __half2 vb = __hfma2(u2h2(bw[k]), u2h2(sb), u2h2(cb)); \
                        __half2 pr = __hmul2(va, vb);                         \
                        sum1[k] = (a1 == 0) ? pr : __hadd2(sum1[k], pr);      \
                    }                                                         \
                }                                                             \
                _Pragma("unroll")                                             \
                for (int k = 0; k < 4; ++k)                                   \
                    prod2[k] = (a2 == 0) ? sum1[k] : __hmul2(prod2[k], sum1[k]); \
            }                                                                 \
            _Pragma("unroll")                                                 \
            for (int k = 0; k < 4; ++k) {                                     \
                float2 pf = __half22float2(prod2[k]);                         \
                accf[2*k]     += pf.x;                                        \
                accf[2*k + 1] += pf.y;                                        \
            }                                                                 \
        }                                                                     \
        float* dst = out + (size_t)(OO) * BATCH + w * 32 + cg * 8;            \
        f32x4 o0 = {accf[0], accf[1], accf[2], accf[3]};                      \
        f32x4 o1 = {accf[4], accf[5], accf[6], accf[7]};                      \
        __builtin_nontemporal_store(o0, reinterpret_cast<f32x4*>(dst));       \
        __builtin_nontemporal_store(o1, reinterpret_cast<f32x4*>(dst) + 1);   \
    } while (0)

// ---------------- main: 512 threads, batched gathers, 2-deep pipeline ---------
// 256 blocks x 512 threads, 1 block/CU (128 KiB LDS), 256-VGPR budget -> the
// 16 ds_read_b128 of a pass are HOISTED into registers (no spill; R10's trap
// was hoisting at 1024 thr / 128 VGPR). Pipeline: pass p+1's 16 gathers and
// pass p+2's T-load issue BEFORE pass p's math -> counted lgkmcnt leaves the
// next batch in flight; exposed LDS latency = 1 batch/pass instead of 8
// serial round-trips (the ~10 us invariant residual of R11..R20).
// XCD k (= bx&7) owns windows 4k..4k+3. 4 passes x 128 outputs.
__global__ __launch_bounds__(512) void knowledge_main(
    const char* __restrict__ xh2,
    const uint4* __restrict__ T4,     // 2 x uint4 per output (8 packed pair-words)
    float* __restrict__ out)
{
    __shared__ char lds[131072];      // window: row r at byte r*64 (32 fp16 cols)

    const int bx    = blockIdx.x;     // 256
    const int tid   = threadIdx.x;    // 0..511
    const int xcd   = bx & 7;
    const int slot  = bx >> 3;        // 0..31
    const int w     = xcd * 4 + (slot & 3);  // window 0..31
    const int chunk = slot >> 2;      // 0..7 (512 outputs each)

    const int cg  = tid & 3;          // col group 0..3 (8 cols = 16 B)
    const int ol  = tid >> 2;         // output-in-pass 0..127
    const int cgb = cg * 16;
    const int ob  = chunk * 512 + ol;

    // ---- T loads for passes 0 and 1 issued BEFORE staging (latency hidden) ----
    uint4 Ta0 = T4[(size_t)ob * 2];
    uint4 Tb0 = T4[(size_t)ob * 2 + 1];
    uint4 Ta1 = T4[(size_t)(ob + 128) * 2];
    uint4 Tb1 = T4[(size_t)(ob + 128) * 2 + 1];

    // ---- stage: linear 128 KiB copy ----
    {
        const char* src = xh2 + (size_t)w * W32BYTES;
        #pragma unroll
        for (int it = 0; it < 16; ++it) {
            const int u = it * 512 + tid;
            *(uint4*)(lds + u * 16) = *(const uint4*)(src + u * 16);
        }
    }
    __syncthreads();

    unsigned TWa[8], TWb[8];
    uint4 Aa[16], Ab[16];

    // pass 0 gathers
    ISSUE16(TWa, Aa, Ta0, Tb0);

    // ---- pass 0: issue G1, load T2, math G0 ----
    ISSUE16(TWb, Ab, Ta1, Tb1);
    Ta0 = T4[(size_t)(ob + 256) * 2];
    Tb0 = T4[(size_t)(ob + 256) * 2 + 1];
    MATHSTORE(TWa, Aa, ob);

    // ---- pass 1: issue G2, load T3, math G1 ----
    ISSUE16(TWa, Aa, Ta0, Tb0);
    Ta1 = T4[(size_t)(ob + 384) * 2];
    Tb1 = T4[(size_t)(ob + 384) * 2 + 1];
    MATHSTORE(TWb, Ab, ob + 128);

    // ---- pass 2: issue G3, math G2 ----
    ISSUE16(TWb, Ab, Ta1, Tb1);
    MATHSTORE(TWa, Aa, ob + 256);

    // ---- pass 3: math G3 ----
    MATHSTORE(TWb, Ab, ob + 384);
}

// ---------------- fallback (round-1 kernel) if ws too small ----------------
__device__ __forceinline__ float Hval(int k, const float* __restrict__ x, int b) {
    if (k < 2) return (float)k;
    float v = x[((k - 2) >> 1) * BATCH + b];
    return (k & 1) ? 1.0f - v : v;
}

__global__ __launch_bounds__(256) void knowledge_fused_kernel(
    const float* __restrict__ x,
    const int2* __restrict__ idx0,
    const int2* __restrict__ idx1,
    const int2* __restrict__ idx2,
    const int2* __restrict__ idx3,
    float* __restrict__ out)
{
    const int i = blockIdx.x;
    const int b = blockIdx.y * blockDim.x + threadIdx.x;
    const int2 p3 = idx3[i];
    float acc3 = 0.0f;
    #pragma unroll
    for (int t = 0; t < 2; ++t) {
        const int2 p2 = idx2[t ? p3.y : p3.x];
        float prod2 = 1.0f;
        #pragma unroll
        for (int u = 0; u < 2; ++u) {
            const int2 p1 = idx1[u ? p2.y : p2.x];
            float sum1 = 0.0f;
            #pragma unroll
            for (int v = 0; v < 2; ++v) {
                const int2 p0 = idx0[v ? p1.y : p1.x];
                sum1 += Hval(p0.x, x, b) * Hval(p0.y, x, b);
            }
            prod2 *= sum1;
        }
        acc3 += prod2;
    }
    out[(size_t)i * BATCH + b] = acc3;
}

extern "C" void kernel_launch(void* const* d_in, const int* in_sizes, int n_in,
                              void* d_out, int out_size, void* d_ws, size_t ws_size,
                              hipStream_t stream) {
    const float* x    = (const float*)d_in[0];
    const int2*  idx0 = (const int2*)d_in[1];
    const int2*  idx1 = (const int2*)d_in[2];
    const int2*  idx2 = (const int2*)d_in[3];
    const int2*  idx3 = (const int2*)d_in[4];
    float* out = (float*)d_out;

    const size_t t_bytes   = (size_t)N_OUT * 8 * sizeof(unsigned);   // 128 KB
    const size_t xh2_bytes = (size_t)NW32 * W32BYTES;                // 4 MB
    if (ws_size >= t_bytes + xh2_bytes) {
        unsigned* T   = (unsigned*)d_ws;
        char*     xh2 = (char*)d_ws + t_bytes;
        prep_kernel<<<256, 256, 0, stream>>>(x, idx0, idx1, idx2, idx3, T, xh2);
        knowledge_main<<<256, 512, 0, stream>>>(xh2, (const uint4*)T, out);
    } else {
        dim3 grid(N_OUT, BATCH / 256);
        knowledge_fused_kernel<<<grid, 256, 0, stream>>>(x, idx0, idx1, idx2, idx3, out);
    }
}